// Round 1
// baseline (230.007 us; speedup 1.0000x reference)
//
#include <hip/hip_runtime.h>

// ActorCriticLoss: continue_probs = sigmoid(logits); lambda_returns = reverse scan.
// B=131072, T=64, f32 in/out. Memory-bound: ~201 MB total traffic -> ~32us floor.

constexpr float GAMMA = 0.997f;
constexpr float LAMDA = 0.95f;
constexpr int T = 64;

__global__ __launch_bounds__(256) void sigmoid_k(const float4* __restrict__ in,
                                                 float4* __restrict__ out, int n4) {
  int i = blockIdx.x * blockDim.x + threadIdx.x;
  const int stride = gridDim.x * blockDim.x;
  for (; i < n4; i += stride) {
    float4 v = in[i];
    float4 o;
    o.x = 1.0f / (1.0f + __expf(-v.x));
    o.y = 1.0f / (1.0f + __expf(-v.y));
    o.z = 1.0f / (1.0f + __expf(-v.z));
    o.w = 1.0f / (1.0f + __expf(-v.w));
    out[i] = o;
  }
}

// One thread per row. Row = 64 floats = 256B -> float4-aligned loads.
// Backward recurrence: carry = v[63]; for t=62..0:
//   ret[t] = r[t] + GAMMA*c[t]*((1-LAMDA)*v[t+1] + LAMDA*carry); carry = ret[t]
__global__ __launch_bounds__(256) void lambda_k(const float* __restrict__ rew,
                                                const float* __restrict__ con,
                                                const float* __restrict__ val,
                                                float* __restrict__ out, int B) {
  const int row = blockIdx.x * blockDim.x + threadIdx.x;
  if (row >= B) return;
  const float4* r4p = (const float4*)(rew + (size_t)row * T);
  const float4* c4p = (const float4*)(con + (size_t)row * T);
  const float4* v4p = (const float4*)(val + (size_t)row * T);
  float* o = out + (size_t)row * (T - 1);

  // Chunk 15 covers t=60..63; t=63 is not an output. carry starts at v[63].
  float4 r4 = r4p[15];
  float4 c4 = c4p[15];
  float4 v4 = v4p[15];
  float carry = v4.w;
  float ret;
  // t=62: vn = v[63] = v4.w (and carry == v[63], so blend == v[63] exactly as ref)
  ret = fmaf(GAMMA * c4.z, fmaf(LAMDA, carry, (1.0f - LAMDA) * v4.w), r4.z); o[62] = ret; carry = ret;
  ret = fmaf(GAMMA * c4.y, fmaf(LAMDA, carry, (1.0f - LAMDA) * v4.z), r4.y); o[61] = ret; carry = ret;
  ret = fmaf(GAMMA * c4.x, fmaf(LAMDA, carry, (1.0f - LAMDA) * v4.y), r4.x); o[60] = ret; carry = ret;
  float vnext = v4.x;  // v[60]

#pragma unroll
  for (int j = 14; j >= 0; --j) {
    r4 = r4p[j];
    c4 = c4p[j];
    v4 = v4p[j];
    const int t = 4 * j;
    // t+3: vn = v[4j+4] = vnext
    ret = fmaf(GAMMA * c4.w, fmaf(LAMDA, carry, (1.0f - LAMDA) * vnext), r4.w); o[t + 3] = ret; carry = ret;
    // t+2: vn = v[4j+3] = v4.w
    ret = fmaf(GAMMA * c4.z, fmaf(LAMDA, carry, (1.0f - LAMDA) * v4.w), r4.z);  o[t + 2] = ret; carry = ret;
    // t+1: vn = v[4j+2] = v4.z
    ret = fmaf(GAMMA * c4.y, fmaf(LAMDA, carry, (1.0f - LAMDA) * v4.z), r4.y);  o[t + 1] = ret; carry = ret;
    // t+0: vn = v[4j+1] = v4.y
    ret = fmaf(GAMMA * c4.x, fmaf(LAMDA, carry, (1.0f - LAMDA) * v4.y), r4.x);  o[t]     = ret; carry = ret;
    vnext = v4.x;  // v[4j]
  }
}

extern "C" void kernel_launch(void* const* d_in, const int* in_sizes, int n_in,
                              void* d_out, int out_size, void* d_ws, size_t ws_size,
                              hipStream_t stream) {
  const float* logits = (const float*)d_in[0];
  const float* rew    = (const float*)d_in[1];
  const float* con    = (const float*)d_in[2];
  const float* val    = (const float*)d_in[3];
  float* out = (float*)d_out;

  const int BT = in_sizes[0];      // B*T
  const int B  = BT / T;
  const int n4 = BT / 4;

  int sblocks = (n4 + 255) / 256;
  if (sblocks > 2048) sblocks = 2048;
  sigmoid_k<<<sblocks, 256, 0, stream>>>((const float4*)logits, (float4*)out, n4);

  const int lblocks = (B + 255) / 256;
  lambda_k<<<lblocks, 256, 0, stream>>>(rew, con, val, out + (size_t)BT, B);
}

// Round 4
// 171.585 us; speedup vs baseline: 1.3405x; 1.3405x over previous
//
#include <hip/hip_runtime.h>

// ActorCriticLoss fused kernel.
//   out[0 .. B*T)        = sigmoid(logits)
//   out[B*T .. B*T+B*63) = lambda returns (reverse affine scan over T)
//
// One wave (64 lanes) per row, lane = timestep t. All global accesses are
// fully coalesced (64 consecutive floats per wave per instruction).
// The recurrence carry_t = a_t*carry_{t+1} + b_t is solved with a 6-step
// Hillis-Steele suffix scan over affine maps (A,B):
//   a_t = GAMMA*LAMDA*c_t
//   b_t = r_t + GAMMA*(1-LAMDA)*c_t*v_{t+1}
//   ret_t = (f_t o f_{t+1} o ... o f_62)(v_63)
// Lane 63 holds the identity map so index-clamped shuffles are harmless.

constexpr float GAMMA = 0.997f;
constexpr float LAMDA = 0.95f;
constexpr int T = 64;

__global__ __launch_bounds__(256) void fused_k(const float* __restrict__ logits,
                                               const float* __restrict__ rew,
                                               const float* __restrict__ con,
                                               const float* __restrict__ val,
                                               float* __restrict__ out_sig,
                                               float* __restrict__ out_ret,
                                               int B) {
  const int tid = blockIdx.x * blockDim.x + threadIdx.x;
  const int row = tid >> 6;          // wave per row
  const int t   = tid & 63;          // lane = timestep
  if (row >= B) return;

  const size_t idx = (size_t)row * T + t;

  // ---- sigmoid (coalesced 256B load + 256B store per wave) ----
  const float x = logits[idx];
  out_sig[idx] = 1.0f / (1.0f + __expf(-x));

  // ---- lambda returns: wave-parallel affine suffix scan ----
  const float r = rew[idx];
  const float c = con[idx];
  const float v = val[idx];

  // v_{t+1}: pull from lane t+1 (clamped; lane 63 doesn't need it)
  const float vnext = __shfl(v, (t < 63) ? t + 1 : 63);

  float A, Bc;
  if (t == 63) {          // identity map: scan boundary
    A = 1.0f; Bc = 0.0f;
  } else {
    A  = (GAMMA * LAMDA) * c;
    Bc = fmaf((GAMMA * (1.0f - LAMDA)) * c, vnext, r);
  }

  // Inclusive suffix scan: after step d, lane t holds f_t o ... o f_{min(t+2d-1,63)}.
  // Lane 63 stays identity, so clamping the source lane to 63 is exact.
#pragma unroll
  for (int d = 1; d < 64; d <<= 1) {
    int src = t + d;
    if (src > 63) src = 63;
    const float Ain = __shfl(A, src);
    const float Bin = __shfl(Bc, src);
    Bc = fmaf(A, Bin, Bc);   // self o src : apply src first
    A  = A * Ain;
  }

  const float v63 = __shfl(v, 63);   // bootstrap = values[:, -1]
  const float ret = fmaf(A, v63, Bc);

  if (t < 63) out_ret[(size_t)row * 63 + t] = ret;  // 252B contiguous per wave
}

extern "C" void kernel_launch(void* const* d_in, const int* in_sizes, int n_in,
                              void* d_out, int out_size, void* d_ws, size_t ws_size,
                              hipStream_t stream) {
  const float* logits = (const float*)d_in[0];
  const float* rew    = (const float*)d_in[1];
  const float* con    = (const float*)d_in[2];
  const float* val    = (const float*)d_in[3];
  float* out = (float*)d_out;

  const int BT = in_sizes[0];   // B*T
  const int B  = BT / T;

  float* out_sig = out;                  // B*T floats
  float* out_ret = out + (size_t)BT;     // B*63 floats

  // one wave per row -> B*64 threads -> B/4 blocks of 256
  const int blocks = B / 4;
  fused_k<<<blocks, 256, 0, stream>>>(logits, rew, con, val, out_sig, out_ret, B);
}